// Round 1
// baseline (545.737 us; speedup 1.0000x reference)
//
#include <hip/hip_runtime.h>
#include <hip/hip_bf16.h>

// ---------------- helpers ----------------
typedef __attribute__((ext_vector_type(8))) short short8;
typedef __attribute__((ext_vector_type(4))) float floatx4;

__device__ __forceinline__ unsigned short f2bfu(float f) {
    unsigned u = __float_as_uint(f);
    unsigned rounding = 0x7fffu + ((u >> 16) & 1u);
    return (unsigned short)((u + rounding) >> 16);
}
__device__ __forceinline__ float bfu2f(unsigned short u) {
    return __uint_as_float(((unsigned)u) << 16);
}

// async global->LDS, 16B per lane; LDS dest = wave-uniform base + lane*16
__device__ __forceinline__ void async_ld16(const void* g, void* l) {
    __builtin_amdgcn_global_load_lds(
        (const __attribute__((address_space(1))) void*)g,
        (__attribute__((address_space(3))) void*)l, 16, 0, 0);
}

#define B_  8
#define N_  2048
#define C_  512
#define NC_ 16   // clusters
#define SL_ 8    // cluster_reduce row slices

// ---------------- convert kernels ----------------
__global__ __launch_bounds__(256) void cvt_x(const float4* __restrict__ x,
                                             unsigned short* __restrict__ xbf) {
    size_t i = (size_t)blockIdx.x * 256 + threadIdx.x;   // 4 floats per thread
    float4 f = x[i];
    unsigned short u0 = f2bfu(f.x), u1 = f2bfu(f.y), u2 = f2bfu(f.z), u3 = f2bfu(f.w);
    uint2 p;
    p.x = (unsigned)u0 | ((unsigned)u1 << 16);
    p.y = (unsigned)u2 | ((unsigned)u3 << 16);
    *(uint2*)(xbf + 4 * i) = p;
}

// WqkvT[n][k], n in [0,1536), k in [0,512): n<1024 -> Wqk[k][n] ; else Wv[k][n-1024]
__global__ __launch_bounds__(256) void cvt_wqkv(const float* __restrict__ Wqk,
                                                const float* __restrict__ Wv,
                                                unsigned short* __restrict__ WT) {
    int id = blockIdx.x * 256 + threadIdx.x;   // 1536*512 total
    int n = id >> 9, k = id & 511;
    float v = (n < 1024) ? Wqk[(size_t)k * 1024 + n] : Wv[(size_t)k * 512 + (n - 1024)];
    WT[id] = f2bfu(v);
}

// ---------------- stable counting sort per batch ----------------
__global__ __launch_bounds__(256) void sort_kernel(const int* __restrict__ idx_cluster,
                                                   int* __restrict__ shuf,
                                                   int* __restrict__ restore,
                                                   int* __restrict__ svals,
                                                   int* __restrict__ dbl,
                                                   int* __restrict__ cstart) {
    int b = blockIdx.x, t = threadIdx.x;
    __shared__ int vals[N_];
    __shared__ int seghist[256 * 17];   // stride 17 to spread banks
    __shared__ int cbase[NC_], ctot[NC_];
    __shared__ int shufs[N_];
    const int* src = idx_cluster + (size_t)b * N_;
    for (int j = t; j < N_; j += 256) vals[j] = src[j];
    for (int c = 0; c < NC_; ++c) seghist[t * 17 + c] = 0;
    __syncthreads();
    // count: thread t owns positions t*8 .. t*8+7 (contiguous -> stable)
    for (int i = 0; i < 8; ++i) {
        int c = vals[t * 8 + i];
        seghist[t * 17 + c]++;
    }
    __syncthreads();
    if (t < NC_) {   // exclusive scan over segments for cluster t
        int run = 0;
        for (int s = 0; s < 256; ++s) {
            int x = seghist[s * 17 + t];
            seghist[s * 17 + t] = run;
            run += x;
        }
        ctot[t] = run;
    }
    __syncthreads();
    if (t == 0) {
        int run = 0;
        for (int c = 0; c < NC_; ++c) {
            cbase[c] = run;
            cstart[b * 17 + c] = run;
            run += ctot[c];
        }
        cstart[b * 17 + NC_] = run;   // == N_
    }
    __syncthreads();
    for (int i = 0; i < 8; ++i) {
        int p = t * 8 + i;
        int c = vals[p];
        int pos = cbase[c] + seghist[t * 17 + c];
        seghist[t * 17 + c]++;
        shufs[pos] = p;
    }
    __syncthreads();
    for (int j = t; j < N_; j += 256) {
        int sj = shufs[j];
        shuf[(size_t)b * N_ + j] = sj;
        svals[(size_t)b * N_ + j] = vals[sj];
        restore[(size_t)b * N_ + sj] = j;
        dbl[(size_t)b * N_ + j] = shufs[sj];
    }
}

// ---------------- bf16 MFMA GEMM, A (MxK) row-major, Bt (NxK) row-major ----------------
// m97 pattern: global_load_lds width=16 staging, unpadded 128x64 LDS tiles,
// source-side XOR swizzle (chunk ^= row&7) to kill ds_read_b128 bank conflicts.
// MODE 0: qkv  (N=1536) -> split bf16 q/k/v
// MODE 1: attn (per-batch 2048x2048) -> f32 * SCALE
template <int MODE>
__global__ __launch_bounds__(256) void gemm_bt(const unsigned short* __restrict__ A,
                                               const unsigned short* __restrict__ Bt,
                                               float* __restrict__ outF,
                                               unsigned short* __restrict__ outQ,
                                               unsigned short* __restrict__ outK,
                                               unsigned short* __restrict__ outV,
                                               const float* __restrict__ bias) {
    constexpr int K = 512;
    int t = threadIdx.x;
    int lane = t & 63, wave = t >> 6;
    int wm = (wave & 1) * 64, wn = (wave >> 1) * 64;
    int m0 = blockIdx.y * 128, n0 = blockIdx.x * 128;
    if (MODE == 1) {
        size_t b = blockIdx.z;
        A += b * (size_t)N_ * 512;
        Bt += b * (size_t)N_ * 512;
        outF += b * (size_t)N_ * N_;
    }
    __shared__ __align__(16) unsigned short As[128 * 64];
    __shared__ __align__(16) unsigned short Bs[128 * 64];
    floatx4 acc[4][4] = {};
    int l15 = lane & 15, q4 = lane >> 4;
    // staging: lane covers row (lane>>3) within its 8-row group, chunk (lane&7)
    int srow = lane >> 3, schk = lane & 7;
    int sgc = schk ^ srow;            // source chunk after XOR swizzle (row&7 == srow)
    int xr = l15 & 7;                 // fragment-read XOR (row&7 == l15&7 for all mi/ni)

    for (int k0 = 0; k0 < K; k0 += 64) {
        __syncthreads();   // previous-iter LDS reads done before overwrite
#pragma unroll
        for (int i = 0; i < 4; ++i) {
            int cid = i * 4 + wave;                 // 1KB group id (16 groups of 8 rows)
            int row = cid * 8 + srow;
            async_ld16(A + (size_t)(m0 + row) * 512 + k0 + sgc * 8, (char*)As + cid * 1024);
            async_ld16(Bt + (size_t)(n0 + row) * 512 + k0 + sgc * 8, (char*)Bs + cid * 1024);
        }
        __syncthreads();   // drains vmcnt (async LDS writes visible)
#pragma unroll
        for (int kk = 0; kk < 2; ++kk) {
            int csw = (((kk * 4 + q4) ^ xr) * 8);   // swizzled chunk offset (elements)
            short8 af[4], bfr[4];
#pragma unroll
            for (int mi = 0; mi < 4; ++mi)
                af[mi] = *(const short8*)(&As[(wm + mi * 16 + l15) * 64 + csw]);
#pragma unroll
            for (int ni = 0; ni < 4; ++ni)
                bfr[ni] = *(const short8*)(&Bs[(wn + ni * 16 + l15) * 64 + csw]);
#pragma unroll
            for (int mi = 0; mi < 4; ++mi)
#pragma unroll
                for (int ni = 0; ni < 4; ++ni)
                    acc[mi][ni] = __builtin_amdgcn_mfma_f32_16x16x32_bf16(af[mi], bfr[ni], acc[mi][ni], 0, 0, 0);
        }
    }
    // epilogue: D[row=q4*4+r][col=l15] per 16x16 tile
#pragma unroll
    for (int mi = 0; mi < 4; ++mi) {
#pragma unroll
        for (int ni = 0; ni < 4; ++ni) {
#pragma unroll
            for (int r = 0; r < 4; ++r) {
                int row = m0 + wm + mi * 16 + q4 * 4 + r;
                int col = n0 + wn + ni * 16 + l15;
                float v = acc[mi][ni][r];
                if (MODE == 0) {
                    unsigned short u = f2bfu(v);
                    if (col < 512)       outQ[(size_t)row * 512 + col] = u;
                    else if (col < 1024) outK[(size_t)row * 512 + col - 512] = u;
                    else                 outV[(size_t)row * 512 + col - 1024] = u;
                } else {
                    outF[(size_t)row * N_ + col] = v * 0.125f;
                }
            }
        }
    }
}

// ---------------- sliced per-(batch,cluster) softmax-collapse reduction ----------------
// e_j = exp(attn[b, dbl[j], j]);  slice sl handles rows i in [n*sl/8, n*(sl+1)/8)
// Opart[b][sl][c][d] = sum_{i in slice} e_i * v[b,shuf[i],d]   (unnormalized)
// Spart[b][sl][c]    = sum_{i in slice} e_i
__global__ __launch_bounds__(256) void cluster_reduce2(const float* __restrict__ attn,
                                                       const int* __restrict__ shuf,
                                                       const int* __restrict__ dbl,
                                                       const int* __restrict__ cstart,
                                                       const unsigned short* __restrict__ vbf,
                                                       float* __restrict__ Opart,
                                                       float* __restrict__ Spart) {
    int c = blockIdx.x, b = blockIdx.y, sl = blockIdx.z, t = threadIdx.x;
    int start = cstart[b * 17 + c], end = cstart[b * 17 + c + 1];
    int n = end - start;
    int i0 = (n * sl) / SL_, i1 = (n * (sl + 1)) / SL_;
    int cnt = i1 - i0;                 // <= ceil(2048/8) = 256
    __shared__ float e_lds[256];
    __shared__ int row_lds[256];
    if (t < cnt) {
        int j = start + i0 + t;
        int dj = dbl[(size_t)b * N_ + j];
        float e = expf(attn[(size_t)b * N_ * N_ + (size_t)dj * N_ + j]);
        e_lds[t] = e;
        row_lds[t] = shuf[(size_t)b * N_ + j];
    }
    __syncthreads();
    if (t == 0) {
        float s = 0.f;
        for (int i = 0; i < cnt; ++i) s += e_lds[i];
        Spart[(b * SL_ + sl) * NC_ + c] = s;
    }
    float a0 = 0.f, a1 = 0.f;
    for (int i = 0; i < cnt; ++i) {
        float e = e_lds[i];
        unsigned u = *(const unsigned*)(vbf + ((size_t)b * N_ + row_lds[i]) * 512 + 2 * t);
        a0 += e * bfu2f((unsigned short)u);
        a1 += e * bfu2f((unsigned short)(u >> 16));
    }
    float2 o; o.x = a0; o.y = a1;
    *(float2*)(Opart + (((size_t)(b * SL_ + sl) * NC_ + c) * 512 + 2 * t)) = o;
}

// ---------------- combine slice partials -> normalized Ot[b][d][c] ----------------
__global__ __launch_bounds__(256) void combine_O(const float* __restrict__ Opart,
                                                 const float* __restrict__ Spart,
                                                 float* __restrict__ Ot) {
    int c = blockIdx.x, b = blockIdx.y, t = threadIdx.x;
    float S = 0.f;
    for (int sl = 0; sl < SL_; ++sl) S += Spart[(b * SL_ + sl) * NC_ + c];
    float inv = S > 0.f ? 1.f / S : 0.f;
    float a0 = 0.f, a1 = 0.f;
    for (int sl = 0; sl < SL_; ++sl) {
        float2 o = *(const float2*)(Opart + (((size_t)(b * SL_ + sl) * NC_ + c) * 512 + 2 * t));
        a0 += o.x; a1 += o.y;
    }
    Ot[((size_t)b * 512 + 2 * t) * NC_ + c] = a0 * inv;
    Ot[((size_t)b * 512 + 2 * t + 1) * NC_ + c] = a1 * inv;
}

// ---------------- grouped projection weights ----------------
// Wg[b][g][c][m] = sum_{cd in [0,512): svals[b][g*512+cd]==c} Wproj[cd][m]   (bf16, u32-paired)
// svals is sorted -> each c is one contiguous run per (b,g): register run-accumulate + flush.
__global__ __launch_bounds__(256) void build_wg(const float* __restrict__ Wproj,
                                                const int* __restrict__ svals,
                                                unsigned int* __restrict__ Wg) {
    int g = blockIdx.x, b = blockIdx.y, t = threadIdx.x;
    __shared__ int slds[512];
    for (int i = t; i < 512; i += 256) slds[i] = svals[(size_t)b * N_ + g * 512 + i];
    __syncthreads();
    unsigned int* base = Wg + (size_t)(b * 4 + g) * NC_ * 256;   // [c][256] u32 (m pairs)
#pragma unroll
    for (int c = 0; c < NC_; ++c) base[c * 256 + t] = 0;         // absent clusters -> 0
    int ccur = slds[0];
    float a0 = 0.f, a1 = 0.f;
    for (int cd = 0; cd < 512; ++cd) {
        int c = slds[cd];                       // block-uniform, non-decreasing
        if (c != ccur) {
            base[ccur * 256 + t] = (unsigned)f2bfu(a0) | ((unsigned)f2bfu(a1) << 16);
            a0 = 0.f; a1 = 0.f; ccur = c;
        }
        float2 w = *(const float2*)(Wproj + (size_t)cd * 512 + 2 * t);
        a0 += w.x; a1 += w.y;
    }
    base[ccur * 256 + t] = (unsigned)f2bfu(a0) | ((unsigned)f2bfu(a1) << 16);
}

// ---------------- final projection: x_out[b,n,m] = sum_c Ot[b,rq,c]*Wg[b,g,c,m] + bias[m] ----
// r = restore[b,n]; rq = r>>2; g = r&3.  K=16 contraction, O stays f32.
__global__ __launch_bounds__(256) void xout_kernel(const float* __restrict__ Ot,
                                                   const unsigned int* __restrict__ Wg,
                                                   const int* __restrict__ restore,
                                                   const float* __restrict__ bias,
                                                   float* __restrict__ xout) {
    int nb = blockIdx.x, b = blockIdx.y, t = threadIdx.x;
    int n0 = nb * 64;
    __shared__ int r_lds[64];
    if (t < 64) r_lds[t] = restore[(size_t)b * N_ + n0 + t];
    __syncthreads();
    float b0 = bias[2 * t], b1 = bias[2 * t + 1];
    const float* Otb = Ot + (size_t)b * 512 * NC_;
    for (int g = 0; g < 4; ++g) {
        const unsigned int* wg = Wg + (size_t)(b * 4 + g) * NC_ * 256 + t;
        float wx[NC_], wy[NC_];
#pragma unroll
        for (int c = 0; c < NC_; ++c) {
            unsigned u = wg[c * 256];
            wx[c] = bfu2f((unsigned short)u);
            wy[c] = bfu2f((unsigned short)(u >> 16));
        }
        for (int i = 0; i < 64; ++i) {
            int r = r_lds[i];                    // block-uniform
            if ((r & 3) != g) continue;          // uniform branch
            int rq = r >> 2;
            const float4* op = (const float4*)(Otb + rq * NC_);
            float o[NC_];
            *(float4*)&o[0]  = op[0];
            *(float4*)&o[4]  = op[1];
            *(float4*)&o[8]  = op[2];
            *(float4*)&o[12] = op[3];
            float a0 = b0, a1 = b1;
#pragma unroll
            for (int c = 0; c < NC_; ++c) { a0 += o[c] * wx[c]; a1 += o[c] * wy[c]; }
            float2 res; res.x = a0; res.y = a1;
            *(float2*)(xout + ((size_t)b * N_ + n0 + i) * 512 + 2 * t) = res;
        }
    }
}

// ---------------- launch ----------------
extern "C" void kernel_launch(void* const* d_in, const int* in_sizes, int n_in,
                              void* d_out, int out_size, void* d_ws, size_t ws_size,
                              hipStream_t stream) {
    const float* x_token = (const float*)d_in[0];
    const int* idx_cluster = (const int*)d_in[2];
    const float* Wqk = (const float*)d_in[4];
    const float* Wv = (const float*)d_in[5];
    const float* Wproj = (const float*)d_in[7];
    const float* bproj = (const float*)d_in[8];

    float* x_out = (float*)d_out;                               // [8][2048][512]
    float* attn = x_out + (size_t)B_ * N_ * C_;                 // [8][2048][2048]

    char* ws = (char*)d_ws;
    size_t off = 0;
    auto alloc = [&](size_t bytes) {
        void* p = ws + off;
        off += (bytes + 255) & ~(size_t)255;
        return p;
    };
    unsigned short* WqkvT = (unsigned short*)alloc(1536 * 512 * 2);
    unsigned short* xbf = (unsigned short*)alloc((size_t)B_ * N_ * C_ * 2);
    unsigned short* qbf = (unsigned short*)alloc((size_t)B_ * N_ * C_ * 2);
    unsigned short* kbf = (unsigned short*)alloc((size_t)B_ * N_ * C_ * 2);
    unsigned short* vbf = (unsigned short*)alloc((size_t)B_ * N_ * C_ * 2);
    int* shuf = (int*)alloc((size_t)B_ * N_ * 4);
    int* restore = (int*)alloc((size_t)B_ * N_ * 4);
    int* svals = (int*)alloc((size_t)B_ * N_ * 4);
    int* dbl = (int*)alloc((size_t)B_ * N_ * 4);
    int* cstart = (int*)alloc(B_ * 17 * 4);
    float* Ot = (float*)alloc((size_t)B_ * 512 * NC_ * 4);
    float* Opart = (float*)alloc((size_t)B_ * SL_ * NC_ * 512 * 4);   // 2 MB
    float* Spart = (float*)alloc((size_t)B_ * SL_ * NC_ * 4);
    unsigned int* Wg = (unsigned int*)alloc((size_t)B_ * 4 * NC_ * 256 * 4);  // bf16 pairs

    // 1. converts
    cvt_x<<<dim3((B_ * N_ * C_) / (256 * 4)), dim3(256), 0, stream>>>((const float4*)x_token, xbf);
    cvt_wqkv<<<dim3((1536 * 512) / 256), dim3(256), 0, stream>>>(Wqk, Wv, WqkvT);

    // 2. stable sort / index tables
    sort_kernel<<<dim3(B_), dim3(256), 0, stream>>>(idx_cluster, shuf, restore, svals, dbl, cstart);

    // 3. grouped projection weights (only needs sort output + Wproj)
    build_wg<<<dim3(4, B_), dim3(256), 0, stream>>>(Wproj, svals, Wg);

    // 4. fused qkv GEMM: [16384x512] @ [512x1536]
    gemm_bt<0><<<dim3(1536 / 128, 16384 / 128, 1), dim3(256), 0, stream>>>(
        xbf, WqkvT, nullptr, qbf, kbf, vbf, nullptr);

    // 5. attn_map = q @ k^T * SCALE  (per batch) -> output chunk 1
    gemm_bt<1><<<dim3(N_ / 128, N_ / 128, B_), dim3(256), 0, stream>>>(
        qbf, kbf, attn, nullptr, nullptr, nullptr, nullptr);

    // 6. sliced softmax-collapse per (batch, cluster, slice)
    cluster_reduce2<<<dim3(NC_, B_, SL_), dim3(256), 0, stream>>>(
        attn, shuf, dbl, cstart, vbf, Opart, Spart);

    // 7. combine slices -> normalized Ot
    combine_O<<<dim3(NC_, B_), dim3(256), 0, stream>>>(Opart, Spart, Ot);

    // 8. x_out = gather-K16-GEMM + bias -> output chunk 0
    xout_kernel<<<dim3(N_ / 64, B_), dim3(256), 0, stream>>>(Ot, Wg, restore, bproj, x_out);
}

// Round 2
// 403.707 us; speedup vs baseline: 1.3518x; 1.3518x over previous
//
#include <hip/hip_runtime.h>
#include <hip/hip_bf16.h>

// ---------------- helpers ----------------
typedef __attribute__((ext_vector_type(8))) short short8;
typedef __attribute__((ext_vector_type(4))) float floatx4;

__device__ __forceinline__ unsigned short f2bfu(float f) {
    unsigned u = __float_as_uint(f);
    unsigned rounding = 0x7fffu + ((u >> 16) & 1u);
    return (unsigned short)((u + rounding) >> 16);
}
__device__ __forceinline__ float bfu2f(unsigned short u) {
    return __uint_as_float(((unsigned)u) << 16);
}

// async global->LDS, 16B per lane; LDS dest = wave-uniform base + lane*16
__device__ __forceinline__ void async_ld16(const void* g, void* l) {
    __builtin_amdgcn_global_load_lds(
        (const __attribute__((address_space(1))) void*)g,
        (__attribute__((address_space(3))) void*)l, 16, 0, 0);
}

#define B_  8
#define N_  2048
#define C_  512
#define NC_ 16   // clusters
#define SL_ 8    // cluster_reduce row slices

// ---------------- convert kernels ----------------
__global__ __launch_bounds__(256) void cvt_x(const float4* __restrict__ x,
                                             unsigned short* __restrict__ xbf) {
    size_t i = (size_t)blockIdx.x * 256 + threadIdx.x;   // 4 floats per thread
    float4 f = x[i];
    unsigned short u0 = f2bfu(f.x), u1 = f2bfu(f.y), u2 = f2bfu(f.z), u3 = f2bfu(f.w);
    uint2 p;
    p.x = (unsigned)u0 | ((unsigned)u1 << 16);
    p.y = (unsigned)u2 | ((unsigned)u3 << 16);
    *(uint2*)(xbf + 4 * i) = p;
}

// WqkvT[n][k], n in [0,1536), k in [0,512): n<1024 -> Wqk[k][n] ; else Wv[k][n-1024]
__global__ __launch_bounds__(256) void cvt_wqkv(const float* __restrict__ Wqk,
                                                const float* __restrict__ Wv,
                                                unsigned short* __restrict__ WT) {
    int id = blockIdx.x * 256 + threadIdx.x;   // 1536*512 total
    int n = id >> 9, k = id & 511;
    float v = (n < 1024) ? Wqk[(size_t)k * 1024 + n] : Wv[(size_t)k * 512 + (n - 1024)];
    WT[id] = f2bfu(v);
}

// ---------------- stable counting sort per batch ----------------
__global__ __launch_bounds__(256) void sort_kernel(const int* __restrict__ idx_cluster,
                                                   int* __restrict__ shuf,
                                                   int* __restrict__ restore,
                                                   int* __restrict__ svals,
                                                   int* __restrict__ dbl,
                                                   int* __restrict__ cstart) {
    int b = blockIdx.x, t = threadIdx.x;
    __shared__ int vals[N_];
    __shared__ int seghist[256 * 17];   // stride 17 to spread banks
    __shared__ int cbase[NC_], ctot[NC_];
    __shared__ int shufs[N_];
    const int* src = idx_cluster + (size_t)b * N_;
    for (int j = t; j < N_; j += 256) vals[j] = src[j];
    for (int c = 0; c < NC_; ++c) seghist[t * 17 + c] = 0;
    __syncthreads();
    // count: thread t owns positions t*8 .. t*8+7 (contiguous -> stable)
    for (int i = 0; i < 8; ++i) {
        int c = vals[t * 8 + i];
        seghist[t * 17 + c]++;
    }
    __syncthreads();
    if (t < NC_) {   // exclusive scan over segments for cluster t
        int run = 0;
        for (int s = 0; s < 256; ++s) {
            int x = seghist[s * 17 + t];
            seghist[s * 17 + t] = run;
            run += x;
        }
        ctot[t] = run;
    }
    __syncthreads();
    if (t == 0) {
        int run = 0;
        for (int c = 0; c < NC_; ++c) {
            cbase[c] = run;
            cstart[b * 17 + c] = run;
            run += ctot[c];
        }
        cstart[b * 17 + NC_] = run;   // == N_
    }
    __syncthreads();
    for (int i = 0; i < 8; ++i) {
        int p = t * 8 + i;
        int c = vals[p];
        int pos = cbase[c] + seghist[t * 17 + c];
        seghist[t * 17 + c]++;
        shufs[pos] = p;
    }
    __syncthreads();
    for (int j = t; j < N_; j += 256) {
        int sj = shufs[j];
        shuf[(size_t)b * N_ + j] = sj;
        svals[(size_t)b * N_ + j] = vals[sj];
        restore[(size_t)b * N_ + sj] = j;
        dbl[(size_t)b * N_ + j] = shufs[sj];
    }
}

// ---------------- bf16 MFMA GEMM, A (MxK) row-major, Bt (NxK) row-major ----------------
// m97 pattern + T3 minimum 2-phase: double-buffered 128x64 LDS tiles, stage tile k+1
// (global_load_lds width=16) BEFORE computing tile k, ONE __syncthreads per K-step
// (its implicit vmcnt(0) drain lands after compute -> load latency hidden).
// Source-side XOR swizzle (chunk ^= row&7) kills ds_read_b128 bank conflicts.
// MODE 0: qkv  (N=1536) -> split bf16 q/k/v
// MODE 1: attn (per-batch 2048x2048) -> f32 * SCALE
template <int MODE>
__global__ __launch_bounds__(256) void gemm_bt(const unsigned short* __restrict__ A,
                                               const unsigned short* __restrict__ Bt,
                                               float* __restrict__ outF,
                                               unsigned short* __restrict__ outQ,
                                               unsigned short* __restrict__ outK,
                                               unsigned short* __restrict__ outV,
                                               const float* __restrict__ bias) {
    constexpr int K = 512;
    constexpr int NT = K / 64;   // 8 K-tiles
    int t = threadIdx.x;
    int lane = t & 63, wave = t >> 6;
    int wm = (wave & 1) * 64, wn = (wave >> 1) * 64;
    int m0 = blockIdx.y * 128, n0 = blockIdx.x * 128;
    if (MODE == 1) {
        size_t b = blockIdx.z;
        A += b * (size_t)N_ * 512;
        Bt += b * (size_t)N_ * 512;
        outF += b * (size_t)N_ * N_;
    }
    __shared__ __align__(16) unsigned short As[2][128 * 64];
    __shared__ __align__(16) unsigned short Bs[2][128 * 64];
    floatx4 acc[4][4] = {};
    int l15 = lane & 15, q4 = lane >> 4;
    // staging: lane covers row (lane>>3) within its 8-row group, chunk (lane&7)
    int srow = lane >> 3, schk = lane & 7;
    int sgc = schk ^ srow;            // source chunk after XOR swizzle (row&7 == srow)
    int xr = l15 & 7;                 // fragment-read XOR (row&7 == l15&7 for all mi/ni)

    auto stage = [&](int buf, int k0) {
#pragma unroll
        for (int i = 0; i < 4; ++i) {
            int cid = i * 4 + wave;                 // 1KB group id (16 groups of 8 rows)
            int row = cid * 8 + srow;
            async_ld16(A + (size_t)(m0 + row) * 512 + k0 + sgc * 8, (char*)As[buf] + cid * 1024);
            async_ld16(Bt + (size_t)(n0 + row) * 512 + k0 + sgc * 8, (char*)Bs[buf] + cid * 1024);
        }
    };
    auto compute = [&](int buf) {
#pragma unroll
        for (int kk = 0; kk < 2; ++kk) {
            int csw = (((kk * 4 + q4) ^ xr) * 8);   // swizzled chunk offset (elements)
            short8 af[4], bfr[4];
#pragma unroll
            for (int mi = 0; mi < 4; ++mi)
                af[mi] = *(const short8*)(&As[buf][(wm + mi * 16 + l15) * 64 + csw]);
#pragma unroll
            for (int ni = 0; ni < 4; ++ni)
                bfr[ni] = *(const short8*)(&Bs[buf][(wn + ni * 16 + l15) * 64 + csw]);
#pragma unroll
            for (int mi = 0; mi < 4; ++mi)
#pragma unroll
                for (int ni = 0; ni < 4; ++ni)
                    acc[mi][ni] = __builtin_amdgcn_mfma_f32_16x16x32_bf16(af[mi], bfr[ni], acc[mi][ni], 0, 0, 0);
        }
    };

    stage(0, 0);
    __syncthreads();                  // drains vmcnt: tile 0 resident
    for (int it = 1; it < NT; ++it) {
        stage(it & 1, it * 64);       // issue next-tile loads (stay in flight over compute)
        compute((it - 1) & 1);        // 32 MFMA on current tile
        __syncthreads();              // implicit vmcnt(0)+lgkmcnt(0) drain, then barrier
    }
    compute((NT - 1) & 1);            // last tile

    // epilogue: D[row=q4*4+r][col=l15] per 16x16 tile
#pragma unroll
    for (int mi = 0; mi < 4; ++mi) {
#pragma unroll
        for (int ni = 0; ni < 4; ++ni) {
#pragma unroll
            for (int r = 0; r < 4; ++r) {
                int row = m0 + wm + mi * 16 + q4 * 4 + r;
                int col = n0 + wn + ni * 16 + l15;
                float v = acc[mi][ni][r];
                if (MODE == 0) {
                    unsigned short u = f2bfu(v);
                    if (col < 512)       outQ[(size_t)row * 512 + col] = u;
                    else if (col < 1024) outK[(size_t)row * 512 + col - 512] = u;
                    else                 outV[(size_t)row * 512 + col - 1024] = u;
                } else {
                    outF[(size_t)row * N_ + col] = v * 0.125f;
                }
            }
        }
    }
}

// ---------------- sliced per-(batch,cluster) softmax-collapse reduction ----------------
// e_j = exp(attn[b, dbl[j], j]);  slice sl handles rows i in [n*sl/8, n*(sl+1)/8)
// Opart[b][sl][c][d] = sum_{i in slice} e_i * v[b,shuf[i],d]   (unnormalized)
// Spart[b][sl][c]    = sum_{i in slice} e_i
__global__ __launch_bounds__(256) void cluster_reduce2(const float* __restrict__ attn,
                                                       const int* __restrict__ shuf,
                                                       const int* __restrict__ dbl,
                                                       const int* __restrict__ cstart,
                                                       const unsigned short* __restrict__ vbf,
                                                       float* __restrict__ Opart,
                                                       float* __restrict__ Spart) {
    int c = blockIdx.x, b = blockIdx.y, sl = blockIdx.z, t = threadIdx.x;
    int start = cstart[b * 17 + c], end = cstart[b * 17 + c + 1];
    int n = end - start;
    int i0 = (n * sl) / SL_, i1 = (n * (sl + 1)) / SL_;
    int cnt = i1 - i0;                 // <= ceil(2048/8) = 256
    __shared__ float e_lds[256];
    __shared__ int row_lds[256];
    if (t < cnt) {
        int j = start + i0 + t;
        int dj = dbl[(size_t)b * N_ + j];
        float e = expf(attn[(size_t)b * N_ * N_ + (size_t)dj * N_ + j]);
        e_lds[t] = e;
        row_lds[t] = shuf[(size_t)b * N_ + j];
    }
    __syncthreads();
    if (t == 0) {
        float s = 0.f;
        for (int i = 0; i < cnt; ++i) s += e_lds[i];
        Spart[(b * SL_ + sl) * NC_ + c] = s;
    }
    float a0 = 0.f, a1 = 0.f;
    for (int i = 0; i < cnt; ++i) {
        float e = e_lds[i];
        unsigned u = *(const unsigned*)(vbf + ((size_t)b * N_ + row_lds[i]) * 512 + 2 * t);
        a0 += e * bfu2f((unsigned short)u);
        a1 += e * bfu2f((unsigned short)(u >> 16));
    }
    float2 o; o.x = a0; o.y = a1;
    *(float2*)(Opart + (((size_t)(b * SL_ + sl) * NC_ + c) * 512 + 2 * t)) = o;
}

// ---------------- combine slice partials -> normalized Ot[b][d][c] ----------------
__global__ __launch_bounds__(256) void combine_O(const float* __restrict__ Opart,
                                                 const float* __restrict__ Spart,
                                                 float* __restrict__ Ot) {
    int c = blockIdx.x, b = blockIdx.y, t = threadIdx.x;
    float S = 0.f;
    for (int sl = 0; sl < SL_; ++sl) S += Spart[(b * SL_ + sl) * NC_ + c];
    float inv = S > 0.f ? 1.f / S : 0.f;
    float a0 = 0.f, a1 = 0.f;
    for (int sl = 0; sl < SL_; ++sl) {
        float2 o = *(const float2*)(Opart + (((size_t)(b * SL_ + sl) * NC_ + c) * 512 + 2 * t));
        a0 += o.x; a1 += o.y;
    }
    Ot[((size_t)b * 512 + 2 * t) * NC_ + c] = a0 * inv;
    Ot[((size_t)b * 512 + 2 * t + 1) * NC_ + c] = a1 * inv;
}

// ---------------- grouped projection weights (parallel, range-based) ----------------
// svals is sorted: cluster c occupies global rows [cstart[b][c], cstart[b][c+1]).
// Within group g (rows [512g, 512(g+1))): Wg[b][g][c][m] = sum_{cd=lo}^{hi-1} Wproj[cd][m],
// lo/hi = cstart clipped into the group window. No svals scan; 512 blocks, coalesced.
__global__ __launch_bounds__(256) void build_wg(const float* __restrict__ Wproj,
                                                const int* __restrict__ cstart,
                                                unsigned int* __restrict__ Wg) {
    int c = blockIdx.x;          // cluster
    int bg = blockIdx.y;         // b*4+g
    int b = bg >> 2, g = bg & 3;
    int t = threadIdx.x;
    int lo = cstart[b * 17 + c] - g * 512;
    int hi = cstart[b * 17 + c + 1] - g * 512;
    lo = lo < 0 ? 0 : lo;
    hi = hi > 512 ? 512 : hi;
    float a0 = 0.f, a1 = 0.f;
    for (int cd = lo; cd < hi; ++cd) {
        float2 w = *(const float2*)(Wproj + (size_t)cd * 512 + 2 * t);
        a0 += w.x; a1 += w.y;
    }
    Wg[(size_t)bg * NC_ * 256 + c * 256 + t] =
        (unsigned)f2bfu(a0) | ((unsigned)f2bfu(a1) << 16);   // empty range -> 0
}

// ---------------- final projection: x_out[b,n,m] = sum_c Ot[b,rq,c]*Wg[b,g,c,m] + bias[m] ----
// r = restore[b,n]; rq = r>>2; g = r&3.  K=16 contraction, O stays f32.
__global__ __launch_bounds__(256) void xout_kernel(const float* __restrict__ Ot,
                                                   const unsigned int* __restrict__ Wg,
                                                   const int* __restrict__ restore,
                                                   const float* __restrict__ bias,
                                                   float* __restrict__ xout) {
    int nb = blockIdx.x, b = blockIdx.y, t = threadIdx.x;
    int n0 = nb * 64;
    __shared__ int r_lds[64];
    if (t < 64) r_lds[t] = restore[(size_t)b * N_ + n0 + t];
    __syncthreads();
    float b0 = bias[2 * t], b1 = bias[2 * t + 1];
    const float* Otb = Ot + (size_t)b * 512 * NC_;
    for (int g = 0; g < 4; ++g) {
        const unsigned int* wg = Wg + (size_t)(b * 4 + g) * NC_ * 256 + t;
        float wx[NC_], wy[NC_];
#pragma unroll
        for (int c = 0; c < NC_; ++c) {
            unsigned u = wg[c * 256];
            wx[c] = bfu2f((unsigned short)u);
            wy[c] = bfu2f((unsigned short)(u >> 16));
        }
        for (int i = 0; i < 64; ++i) {
            int r = r_lds[i];                    // block-uniform
            if ((r & 3) != g) continue;          // uniform branch
            int rq = r >> 2;
            const float4* op = (const float4*)(Otb + rq * NC_);
            float o[NC_];
            *(float4*)&o[0]  = op[0];
            *(float4*)&o[4]  = op[1];
            *(float4*)&o[8]  = op[2];
            *(float4*)&o[12] = op[3];
            float a0 = b0, a1 = b1;
#pragma unroll
            for (int c = 0; c < NC_; ++c) { a0 += o[c] * wx[c]; a1 += o[c] * wy[c]; }
            float2 res; res.x = a0; res.y = a1;
            *(float2*)(xout + ((size_t)b * N_ + n0 + i) * 512 + 2 * t) = res;
        }
    }
}

// ---------------- launch ----------------
extern "C" void kernel_launch(void* const* d_in, const int* in_sizes, int n_in,
                              void* d_out, int out_size, void* d_ws, size_t ws_size,
                              hipStream_t stream) {
    const float* x_token = (const float*)d_in[0];
    const int* idx_cluster = (const int*)d_in[2];
    const float* Wqk = (const float*)d_in[4];
    const float* Wv = (const float*)d_in[5];
    const float* Wproj = (const float*)d_in[7];
    const float* bproj = (const float*)d_in[8];

    float* x_out = (float*)d_out;                               // [8][2048][512]
    float* attn = x_out + (size_t)B_ * N_ * C_;                 // [8][2048][2048]

    char* ws = (char*)d_ws;
    size_t off = 0;
    auto alloc = [&](size_t bytes) {
        void* p = ws + off;
        off += (bytes + 255) & ~(size_t)255;
        return p;
    };
    unsigned short* WqkvT = (unsigned short*)alloc(1536 * 512 * 2);
    unsigned short* xbf = (unsigned short*)alloc((size_t)B_ * N_ * C_ * 2);
    unsigned short* qbf = (unsigned short*)alloc((size_t)B_ * N_ * C_ * 2);
    unsigned short* kbf = (unsigned short*)alloc((size_t)B_ * N_ * C_ * 2);
    unsigned short* vbf = (unsigned short*)alloc((size_t)B_ * N_ * C_ * 2);
    int* shuf = (int*)alloc((size_t)B_ * N_ * 4);
    int* restore = (int*)alloc((size_t)B_ * N_ * 4);
    int* svals = (int*)alloc((size_t)B_ * N_ * 4);
    int* dbl = (int*)alloc((size_t)B_ * N_ * 4);
    int* cstart = (int*)alloc(B_ * 17 * 4);
    float* Ot = (float*)alloc((size_t)B_ * 512 * NC_ * 4);
    float* Opart = (float*)alloc((size_t)B_ * SL_ * NC_ * 512 * 4);   // 2 MB
    float* Spart = (float*)alloc((size_t)B_ * SL_ * NC_ * 4);
    unsigned int* Wg = (unsigned int*)alloc((size_t)B_ * 4 * NC_ * 256 * 4);  // bf16 pairs

    // 1. converts
    cvt_x<<<dim3((B_ * N_ * C_) / (256 * 4)), dim3(256), 0, stream>>>((const float4*)x_token, xbf);
    cvt_wqkv<<<dim3((1536 * 512) / 256), dim3(256), 0, stream>>>(Wqk, Wv, WqkvT);

    // 2. stable sort / index tables
    sort_kernel<<<dim3(B_), dim3(256), 0, stream>>>(idx_cluster, shuf, restore, svals, dbl, cstart);

    // 3. grouped projection weights (range-based from cstart)
    build_wg<<<dim3(NC_, B_ * 4), dim3(256), 0, stream>>>(Wproj, cstart, Wg);

    // 4. fused qkv GEMM: [16384x512] @ [512x1536]
    gemm_bt<0><<<dim3(1536 / 128, 16384 / 128, 1), dim3(256), 0, stream>>>(
        xbf, WqkvT, nullptr, qbf, kbf, vbf, nullptr);

    // 5. attn_map = q @ k^T * SCALE  (per batch) -> output chunk 1
    gemm_bt<1><<<dim3(N_ / 128, N_ / 128, B_), dim3(256), 0, stream>>>(
        qbf, kbf, attn, nullptr, nullptr, nullptr, nullptr);

    // 6. sliced softmax-collapse per (batch, cluster, slice)
    cluster_reduce2<<<dim3(NC_, B_, SL_), dim3(256), 0, stream>>>(
        attn, shuf, dbl, cstart, vbf, Opart, Spart);

    // 7. combine slices -> normalized Ot
    combine_O<<<dim3(NC_, B_), dim3(256), 0, stream>>>(Opart, Spart, Ot);

    // 8. x_out = gather-K16-GEMM + bias -> output chunk 0
    xout_kernel<<<dim3(N_ / 64, B_), dim3(256), 0, stream>>>(Ot, Wg, restore, bproj, x_out);
}

// Round 3
// 377.108 us; speedup vs baseline: 1.4472x; 1.0705x over previous
//
#include <hip/hip_runtime.h>
#include <hip/hip_bf16.h>

// ---------------- helpers ----------------
typedef __attribute__((ext_vector_type(8))) short short8;
typedef __attribute__((ext_vector_type(4))) float floatx4;

__device__ __forceinline__ unsigned short f2bfu(float f) {
    unsigned u = __float_as_uint(f);
    unsigned rounding = 0x7fffu + ((u >> 16) & 1u);
    return (unsigned short)((u + rounding) >> 16);
}
__device__ __forceinline__ float bfu2f(unsigned short u) {
    return __uint_as_float(((unsigned)u) << 16);
}

// async global->LDS, 16B per lane; LDS dest = wave-uniform base + lane*16
__device__ __forceinline__ void async_ld16(const void* g, void* l) {
    __builtin_amdgcn_global_load_lds(
        (const __attribute__((address_space(1))) void*)g,
        (__attribute__((address_space(3))) void*)l, 16, 0, 0);
}

#define B_  8
#define N_  2048
#define C_  512
#define NC_ 16   // clusters
#define SL_ 8    // cluster_reduce row slices

// ---------------- convert kernels ----------------
__global__ __launch_bounds__(256) void cvt_x(const float4* __restrict__ x,
                                             unsigned short* __restrict__ xbf) {
    size_t i = (size_t)blockIdx.x * 256 + threadIdx.x;   // 4 floats per thread
    float4 f = x[i];
    unsigned short u0 = f2bfu(f.x), u1 = f2bfu(f.y), u2 = f2bfu(f.z), u3 = f2bfu(f.w);
    uint2 p;
    p.x = (unsigned)u0 | ((unsigned)u1 << 16);
    p.y = (unsigned)u2 | ((unsigned)u3 << 16);
    *(uint2*)(xbf + 4 * i) = p;
}

// WqkvT[n][k], n in [0,1536), k in [0,512): n<1024 -> Wqk[k][n] ; else Wv[k][n-1024]
__global__ __launch_bounds__(256) void cvt_wqkv(const float* __restrict__ Wqk,
                                                const float* __restrict__ Wv,
                                                unsigned short* __restrict__ WT) {
    int id = blockIdx.x * 256 + threadIdx.x;   // 1536*512 total
    int n = id >> 9, k = id & 511;
    float v = (n < 1024) ? Wqk[(size_t)k * 1024 + n] : Wv[(size_t)k * 512 + (n - 1024)];
    WT[id] = f2bfu(v);
}

// ---------------- stable counting sort per batch ----------------
__global__ __launch_bounds__(256) void sort_kernel(const int* __restrict__ idx_cluster,
                                                   int* __restrict__ shuf,
                                                   int* __restrict__ restore,
                                                   int* __restrict__ svals,
                                                   int* __restrict__ dbl,
                                                   int* __restrict__ cstart) {
    int b = blockIdx.x, t = threadIdx.x;
    __shared__ int vals[N_];
    __shared__ int seghist[256 * 17];   // stride 17 to spread banks
    __shared__ int cbase[NC_], ctot[NC_];
    __shared__ int shufs[N_];
    const int* src = idx_cluster + (size_t)b * N_;
    for (int j = t; j < N_; j += 256) vals[j] = src[j];
    for (int c = 0; c < NC_; ++c) seghist[t * 17 + c] = 0;
    __syncthreads();
    // count: thread t owns positions t*8 .. t*8+7 (contiguous -> stable)
    for (int i = 0; i < 8; ++i) {
        int c = vals[t * 8 + i];
        seghist[t * 17 + c]++;
    }
    __syncthreads();
    if (t < NC_) {   // exclusive scan over segments for cluster t
        int run = 0;
        for (int s = 0; s < 256; ++s) {
            int x = seghist[s * 17 + t];
            seghist[s * 17 + t] = run;
            run += x;
        }
        ctot[t] = run;
    }
    __syncthreads();
    if (t == 0) {
        int run = 0;
        for (int c = 0; c < NC_; ++c) {
            cbase[c] = run;
            cstart[b * 17 + c] = run;
            run += ctot[c];
        }
        cstart[b * 17 + NC_] = run;   // == N_
    }
    __syncthreads();
    for (int i = 0; i < 8; ++i) {
        int p = t * 8 + i;
        int c = vals[p];
        int pos = cbase[c] + seghist[t * 17 + c];
        seghist[t * 17 + c]++;
        shufs[pos] = p;
    }
    __syncthreads();
    for (int j = t; j < N_; j += 256) {
        int sj = shufs[j];
        shuf[(size_t)b * N_ + j] = sj;
        svals[(size_t)b * N_ + j] = vals[sj];
        restore[(size_t)b * N_ + sj] = j;
        dbl[(size_t)b * N_ + j] = shufs[sj];
    }
}

// ---------------- bf16 MFMA GEMM, A (MxK) row-major, Bt (NxK) row-major ----------------
// 128x128 tile, BK=32 DOUBLE-buffered (32 KiB LDS total -> occupancy preserved vs R0).
// Per K-step: issue next-tile global_load_lds BEFORE the 16 MFMAs, single
// __syncthreads (its implicit vmcnt(0) drain waits only the latency remainder).
// LDS swizzle for 64B rows: chunk slot = chunk ^ ((row>>1)&3); staging pre-swizzles
// the GLOBAL source chunk (LDS stays linear for global_load_lds), fragment reads
// use q4 ^ ((l15>>1)&3) -> 2-way bank aliasing only (free).
// Bijective XCD swizzle on the flattened block id (nwg % 8 == 0 for both uses);
// for MODE 1 each XCD maps to one batch (q+k = 4MB = one XCD L2).
// MODE 0: qkv  (N=1536) -> split bf16 q/k/v
// MODE 1: attn (per-batch 2048x2048) -> f32 * SCALE
template <int MODE>
__global__ __launch_bounds__(256) void gemm_bt(const unsigned short* __restrict__ A,
                                               const unsigned short* __restrict__ Bt,
                                               float* __restrict__ outF,
                                               unsigned short* __restrict__ outQ,
                                               unsigned short* __restrict__ outK,
                                               unsigned short* __restrict__ outV,
                                               const float* __restrict__ bias) {
    constexpr int K = 512;
    constexpr int NT = K / 32;   // 16 K-tiles
    int t = threadIdx.x;
    int lane = t & 63, wave = t >> 6;
    int wm = (wave & 1) * 64, wn = (wave >> 1) * 64;

    // ---- bijective XCD swizzle of the flattened block id ----
    int gx = gridDim.x, gy = gridDim.y;
    int nwg = gx * gy * gridDim.z;                    // divisible by 8
    int lid = blockIdx.x + gx * (blockIdx.y + gy * blockIdx.z);
    int swz = (lid & 7) * (nwg >> 3) + (lid >> 3);
    int bx = swz % gx;
    int rem = swz / gx;
    int by = rem % gy;
    int bz = rem / gy;

    int m0 = by * 128, n0 = bx * 128;
    if (MODE == 1) {
        size_t b = (size_t)bz;
        A += b * (size_t)N_ * 512;
        Bt += b * (size_t)N_ * 512;
        outF += b * (size_t)N_ * N_;
    }
    __shared__ __align__(16) unsigned short As[2][128 * 32];
    __shared__ __align__(16) unsigned short Bs[2][128 * 32];
    floatx4 acc[4][4] = {};
    int l15 = lane & 15, q4 = lane >> 4;
    int fc = (l15 >> 1) & 3;             // fragment chunk XOR

    // staging: 1KB group = 16 rows x 64B; lane covers row grp*16+(lane>>2), slot lane&3.
    int s_r = lane >> 2;                 // row within group
    int s_c = (lane & 3) ^ ((lane >> 3) & 3);   // pre-swizzled global chunk

    auto stage = [&](int buf, int k0) {
#pragma unroll
        for (int i = 0; i < 2; ++i) {
            int grp = wave + i * 4;                  // 0..7 (8 groups of 16 rows)
            int row = grp * 16 + s_r;
            async_ld16(A + (size_t)(m0 + row) * 512 + k0 + s_c * 8, (char*)As[buf] + grp * 1024);
            async_ld16(Bt + (size_t)(n0 + row) * 512 + k0 + s_c * 8, (char*)Bs[buf] + grp * 1024);
        }
    };
    auto compute = [&](int buf) {
        int cs = (q4 ^ fc) * 8;                      // swizzled chunk offset (elements)
        short8 af[4], bfr[4];
#pragma unroll
        for (int mi = 0; mi < 4; ++mi)
            af[mi] = *(const short8*)(&As[buf][(wm + mi * 16 + l15) * 32 + cs]);
#pragma unroll
        for (int ni = 0; ni < 4; ++ni)
            bfr[ni] = *(const short8*)(&Bs[buf][(wn + ni * 16 + l15) * 32 + cs]);
#pragma unroll
        for (int mi = 0; mi < 4; ++mi)
#pragma unroll
            for (int ni = 0; ni < 4; ++ni)
                acc[mi][ni] = __builtin_amdgcn_mfma_f32_16x16x32_bf16(af[mi], bfr[ni], acc[mi][ni], 0, 0, 0);
    };

    stage(0, 0);
    __syncthreads();                     // tile 0 resident
    for (int it = 1; it < NT; ++it) {
        stage(it & 1, it * 32);          // next tile in flight over compute
        compute((it - 1) & 1);
        __syncthreads();                 // drain vmcnt remainder + barrier
    }
    compute((NT - 1) & 1);

    // epilogue: D[row=q4*4+r][col=l15] per 16x16 tile
#pragma unroll
    for (int mi = 0; mi < 4; ++mi) {
#pragma unroll
        for (int ni = 0; ni < 4; ++ni) {
#pragma unroll
            for (int r = 0; r < 4; ++r) {
                int row = m0 + wm + mi * 16 + q4 * 4 + r;
                int col = n0 + wn + ni * 16 + l15;
                float v = acc[mi][ni][r];
                if (MODE == 0) {
                    unsigned short u = f2bfu(v);
                    if (col < 512)       outQ[(size_t)row * 512 + col] = u;
                    else if (col < 1024) outK[(size_t)row * 512 + col - 512] = u;
                    else                 outV[(size_t)row * 512 + col - 1024] = u;
                } else {
                    outF[(size_t)row * N_ + col] = v * 0.125f;
                }
            }
        }
    }
}

// ---------------- sliced per-(batch,cluster) softmax-collapse reduction ----------------
// e_j = exp(attn[b, dbl[j], j]);  slice sl handles rows i in [n*sl/8, n*(sl+1)/8)
// Opart[b][sl][c][d] = sum_{i in slice} e_i * v[b,shuf[i],d]   (unnormalized)
// Spart[b][sl][c]    = sum_{i in slice} e_i
__global__ __launch_bounds__(256) void cluster_reduce2(const float* __restrict__ attn,
                                                       const int* __restrict__ shuf,
                                                       const int* __restrict__ dbl,
                                                       const int* __restrict__ cstart,
                                                       const unsigned short* __restrict__ vbf,
                                                       float* __restrict__ Opart,
                                                       float* __restrict__ Spart) {
    int c = blockIdx.x, b = blockIdx.y, sl = blockIdx.z, t = threadIdx.x;
    int start = cstart[b * 17 + c], end = cstart[b * 17 + c + 1];
    int n = end - start;
    int i0 = (n * sl) / SL_, i1 = (n * (sl + 1)) / SL_;
    int cnt = i1 - i0;                 // <= ceil(2048/8) = 256
    __shared__ float e_lds[256];
    __shared__ int row_lds[256];
    if (t < cnt) {
        int j = start + i0 + t;
        int dj = dbl[(size_t)b * N_ + j];
        float e = expf(attn[(size_t)b * N_ * N_ + (size_t)dj * N_ + j]);
        e_lds[t] = e;
        row_lds[t] = shuf[(size_t)b * N_ + j];
    }
    __syncthreads();
    if (t == 0) {
        float s = 0.f;
        for (int i = 0; i < cnt; ++i) s += e_lds[i];
        Spart[(b * SL_ + sl) * NC_ + c] = s;
    }
    float a0 = 0.f, a1 = 0.f;
    for (int i = 0; i < cnt; ++i) {
        float e = e_lds[i];
        unsigned u = *(const unsigned*)(vbf + ((size_t)b * N_ + row_lds[i]) * 512 + 2 * t);
        a0 += e * bfu2f((unsigned short)u);
        a1 += e * bfu2f((unsigned short)(u >> 16));
    }
    float2 o; o.x = a0; o.y = a1;
    *(float2*)(Opart + (((size_t)(b * SL_ + sl) * NC_ + c) * 512 + 2 * t)) = o;
}

// ---------------- combine slice partials -> normalized Ot[b][d][c] ----------------
__global__ __launch_bounds__(256) void combine_O(const float* __restrict__ Opart,
                                                 const float* __restrict__ Spart,
                                                 float* __restrict__ Ot) {
    int c = blockIdx.x, b = blockIdx.y, t = threadIdx.x;
    float S = 0.f;
    for (int sl = 0; sl < SL_; ++sl) S += Spart[(b * SL_ + sl) * NC_ + c];
    float inv = S > 0.f ? 1.f / S : 0.f;
    float a0 = 0.f, a1 = 0.f;
    for (int sl = 0; sl < SL_; ++sl) {
        float2 o = *(const float2*)(Opart + (((size_t)(b * SL_ + sl) * NC_ + c) * 512 + 2 * t));
        a0 += o.x; a1 += o.y;
    }
    Ot[((size_t)b * 512 + 2 * t) * NC_ + c] = a0 * inv;
    Ot[((size_t)b * 512 + 2 * t + 1) * NC_ + c] = a1 * inv;
}

// ---------------- grouped projection weights (parallel, range-based) ----------------
// svals is sorted: cluster c occupies global rows [cstart[b][c], cstart[b][c+1]).
// Within group g (rows [512g, 512(g+1))): Wg[b][g][c][m] = sum_{cd=lo}^{hi-1} Wproj[cd][m],
// lo/hi = cstart clipped into the group window. No svals scan; 512 blocks, coalesced.
__global__ __launch_bounds__(256) void build_wg(const float* __restrict__ Wproj,
                                                const int* __restrict__ cstart,
                                                unsigned int* __restrict__ Wg) {
    int c = blockIdx.x;          // cluster
    int bg = blockIdx.y;         // b*4+g
    int b = bg >> 2, g = bg & 3;
    int t = threadIdx.x;
    int lo = cstart[b * 17 + c] - g * 512;
    int hi = cstart[b * 17 + c + 1] - g * 512;
    lo = lo < 0 ? 0 : lo;
    hi = hi > 512 ? 512 : hi;
    float a0 = 0.f, a1 = 0.f;
    for (int cd = lo; cd < hi; ++cd) {
        float2 w = *(const float2*)(Wproj + (size_t)cd * 512 + 2 * t);
        a0 += w.x; a1 += w.y;
    }
    Wg[(size_t)bg * NC_ * 256 + c * 256 + t] =
        (unsigned)f2bfu(a0) | ((unsigned)f2bfu(a1) << 16);   // empty range -> 0
}

// ---------------- final projection: x_out[b,n,m] = sum_c Ot[b,rq,c]*Wg[b,g,c,m] + bias[m] ----
// r = restore[b,n]; rq = r>>2; g = r&3.  K=16 contraction, O stays f32.
__global__ __launch_bounds__(256) void xout_kernel(const float* __restrict__ Ot,
                                                   const unsigned int* __restrict__ Wg,
                                                   const int* __restrict__ restore,
                                                   const float* __restrict__ bias,
                                                   float* __restrict__ xout) {
    int nb = blockIdx.x, b = blockIdx.y, t = threadIdx.x;
    int n0 = nb * 64;
    __shared__ int r_lds[64];
    if (t < 64) r_lds[t] = restore[(size_t)b * N_ + n0 + t];
    __syncthreads();
    float b0 = bias[2 * t], b1 = bias[2 * t + 1];
    const float* Otb = Ot + (size_t)b * 512 * NC_;
    for (int g = 0; g < 4; ++g) {
        const unsigned int* wg = Wg + (size_t)(b * 4 + g) * NC_ * 256 + t;
        float wx[NC_], wy[NC_];
#pragma unroll
        for (int c = 0; c < NC_; ++c) {
            unsigned u = wg[c * 256];
            wx[c] = bfu2f((unsigned short)u);
            wy[c] = bfu2f((unsigned short)(u >> 16));
        }
        for (int i = 0; i < 64; ++i) {
            int r = r_lds[i];                    // block-uniform
            if ((r & 3) != g) continue;          // uniform branch
            int rq = r >> 2;
            const float4* op = (const float4*)(Otb + rq * NC_);
            float o[NC_];
            *(float4*)&o[0]  = op[0];
            *(float4*)&o[4]  = op[1];
            *(float4*)&o[8]  = op[2];
            *(float4*)&o[12] = op[3];
            float a0 = b0, a1 = b1;
#pragma unroll
            for (int c = 0; c < NC_; ++c) { a0 += o[c] * wx[c]; a1 += o[c] * wy[c]; }
            float2 res; res.x = a0; res.y = a1;
            *(float2*)(xout + ((size_t)b * N_ + n0 + i) * 512 + 2 * t) = res;
        }
    }
}

// ---------------- launch ----------------
extern "C" void kernel_launch(void* const* d_in, const int* in_sizes, int n_in,
                              void* d_out, int out_size, void* d_ws, size_t ws_size,
                              hipStream_t stream) {
    const float* x_token = (const float*)d_in[0];
    const int* idx_cluster = (const int*)d_in[2];
    const float* Wqk = (const float*)d_in[4];
    const float* Wv = (const float*)d_in[5];
    const float* Wproj = (const float*)d_in[7];
    const float* bproj = (const float*)d_in[8];

    float* x_out = (float*)d_out;                               // [8][2048][512]
    float* attn = x_out + (size_t)B_ * N_ * C_;                 // [8][2048][2048]

    char* ws = (char*)d_ws;
    size_t off = 0;
    auto alloc = [&](size_t bytes) {
        void* p = ws + off;
        off += (bytes + 255) & ~(size_t)255;
        return p;
    };
    unsigned short* WqkvT = (unsigned short*)alloc(1536 * 512 * 2);
    unsigned short* xbf = (unsigned short*)alloc((size_t)B_ * N_ * C_ * 2);
    unsigned short* qbf = (unsigned short*)alloc((size_t)B_ * N_ * C_ * 2);
    unsigned short* kbf = (unsigned short*)alloc((size_t)B_ * N_ * C_ * 2);
    unsigned short* vbf = (unsigned short*)alloc((size_t)B_ * N_ * C_ * 2);
    int* shuf = (int*)alloc((size_t)B_ * N_ * 4);
    int* restore = (int*)alloc((size_t)B_ * N_ * 4);
    int* svals = (int*)alloc((size_t)B_ * N_ * 4);
    int* dbl = (int*)alloc((size_t)B_ * N_ * 4);
    int* cstart = (int*)alloc(B_ * 17 * 4);
    float* Ot = (float*)alloc((size_t)B_ * 512 * NC_ * 4);
    float* Opart = (float*)alloc((size_t)B_ * SL_ * NC_ * 512 * 4);   // 2 MB
    float* Spart = (float*)alloc((size_t)B_ * SL_ * NC_ * 4);
    unsigned int* Wg = (unsigned int*)alloc((size_t)B_ * 4 * NC_ * 256 * 4);  // bf16 pairs

    // 1. converts
    cvt_x<<<dim3((B_ * N_ * C_) / (256 * 4)), dim3(256), 0, stream>>>((const float4*)x_token, xbf);
    cvt_wqkv<<<dim3((1536 * 512) / 256), dim3(256), 0, stream>>>(Wqk, Wv, WqkvT);

    // 2. stable sort / index tables
    sort_kernel<<<dim3(B_), dim3(256), 0, stream>>>(idx_cluster, shuf, restore, svals, dbl, cstart);

    // 3. grouped projection weights (range-based from cstart)
    build_wg<<<dim3(NC_, B_ * 4), dim3(256), 0, stream>>>(Wproj, cstart, Wg);

    // 4. fused qkv GEMM: [16384x512] @ [512x1536]
    gemm_bt<0><<<dim3(1536 / 128, 16384 / 128, 1), dim3(256), 0, stream>>>(
        xbf, WqkvT, nullptr, qbf, kbf, vbf, nullptr);

    // 5. attn_map = q @ k^T * SCALE  (per batch) -> output chunk 1
    gemm_bt<1><<<dim3(N_ / 128, N_ / 128, B_), dim3(256), 0, stream>>>(
        qbf, kbf, attn, nullptr, nullptr, nullptr, nullptr);

    // 6. sliced softmax-collapse per (batch, cluster, slice)
    cluster_reduce2<<<dim3(NC_, B_, SL_), dim3(256), 0, stream>>>(
        attn, shuf, dbl, cstart, vbf, Opart, Spart);

    // 7. combine slices -> normalized Ot
    combine_O<<<dim3(NC_, B_), dim3(256), 0, stream>>>(Opart, Spart, Ot);

    // 8. x_out = gather-K16-GEMM + bias -> output chunk 0
    xout_kernel<<<dim3(N_ / 64, B_), dim3(256), 0, stream>>>(Ot, Wg, restore, bproj, x_out);
}

// Round 4
// 365.738 us; speedup vs baseline: 1.4922x; 1.0311x over previous
//
#include <hip/hip_runtime.h>
#include <hip/hip_bf16.h>

// ---------------- helpers ----------------
typedef __attribute__((ext_vector_type(8))) short short8;
typedef __attribute__((ext_vector_type(4))) float floatx4;

__device__ __forceinline__ unsigned short f2bfu(float f) {
    unsigned u = __float_as_uint(f);
    unsigned rounding = 0x7fffu + ((u >> 16) & 1u);
    return (unsigned short)((u + rounding) >> 16);
}
__device__ __forceinline__ float bfu2f(unsigned short u) {
    return __uint_as_float(((unsigned)u) << 16);
}

// async global->LDS, 16B per lane; LDS dest = wave-uniform base + lane*16
__device__ __forceinline__ void async_ld16(const void* g, void* l) {
    __builtin_amdgcn_global_load_lds(
        (const __attribute__((address_space(1))) void*)g,
        (__attribute__((address_space(3))) void*)l, 16, 0, 0);
}

#define B_  8
#define N_  2048
#define C_  512
#define NC_ 16   // clusters
#define SL_ 8    // cluster_reduce row slices

// ---------------- convert kernels ----------------
__global__ __launch_bounds__(256) void cvt_x(const float4* __restrict__ x,
                                             unsigned short* __restrict__ xbf) {
    size_t i = (size_t)blockIdx.x * 256 + threadIdx.x;   // 4 floats per thread
    float4 f = x[i];
    unsigned short u0 = f2bfu(f.x), u1 = f2bfu(f.y), u2 = f2bfu(f.z), u3 = f2bfu(f.w);
    uint2 p;
    p.x = (unsigned)u0 | ((unsigned)u1 << 16);
    p.y = (unsigned)u2 | ((unsigned)u3 << 16);
    *(uint2*)(xbf + 4 * i) = p;
}

// WqkvT[n][k], n in [0,1536), k in [0,512): n<1024 -> Wqk[k][n] ; else Wv[k][n-1024]
__global__ __launch_bounds__(256) void cvt_wqkv(const float* __restrict__ Wqk,
                                                const float* __restrict__ Wv,
                                                unsigned short* __restrict__ WT) {
    int id = blockIdx.x * 256 + threadIdx.x;   // 1536*512 total
    int n = id >> 9, k = id & 511;
    float v = (n < 1024) ? Wqk[(size_t)k * 1024 + n] : Wv[(size_t)k * 512 + (n - 1024)];
    WT[id] = f2bfu(v);
}

// ---------------- stable counting sort per batch ----------------
__global__ __launch_bounds__(256) void sort_kernel(const int* __restrict__ idx_cluster,
                                                   int* __restrict__ shuf,
                                                   int* __restrict__ restore,
                                                   int* __restrict__ svals,
                                                   int* __restrict__ dbl,
                                                   int* __restrict__ cstart) {
    int b = blockIdx.x, t = threadIdx.x;
    __shared__ int vals[N_];
    __shared__ int seghist[256 * 17];   // stride 17 to spread banks
    __shared__ int cbase[NC_], ctot[NC_];
    __shared__ int shufs[N_];
    const int* src = idx_cluster + (size_t)b * N_;
    for (int j = t; j < N_; j += 256) vals[j] = src[j];
    for (int c = 0; c < NC_; ++c) seghist[t * 17 + c] = 0;
    __syncthreads();
    // count: thread t owns positions t*8 .. t*8+7 (contiguous -> stable)
    for (int i = 0; i < 8; ++i) {
        int c = vals[t * 8 + i];
        seghist[t * 17 + c]++;
    }
    __syncthreads();
    if (t < NC_) {   // exclusive scan over segments for cluster t
        int run = 0;
        for (int s = 0; s < 256; ++s) {
            int x = seghist[s * 17 + t];
            seghist[s * 17 + t] = run;
            run += x;
        }
        ctot[t] = run;
    }
    __syncthreads();
    if (t == 0) {
        int run = 0;
        for (int c = 0; c < NC_; ++c) {
            cbase[c] = run;
            cstart[b * 17 + c] = run;
            run += ctot[c];
        }
        cstart[b * 17 + NC_] = run;   // == N_
    }
    __syncthreads();
    for (int i = 0; i < 8; ++i) {
        int p = t * 8 + i;
        int c = vals[p];
        int pos = cbase[c] + seghist[t * 17 + c];
        seghist[t * 17 + c]++;
        shufs[pos] = p;
    }
    __syncthreads();
    for (int j = t; j < N_; j += 256) {
        int sj = shufs[j];
        shuf[(size_t)b * N_ + j] = sj;
        svals[(size_t)b * N_ + j] = vals[sj];
        restore[(size_t)b * N_ + sj] = j;
        dbl[(size_t)b * N_ + j] = shufs[sj];
    }
}

// ---------------- bf16 MFMA GEMM, A (MxK) row-major, Bt (NxK) row-major ----------------
// 128x128 tile, BK=32, THREE LDS buffers (48 KiB -> 3 blocks/CU), prefetch distance 2,
// T4 counted vmcnt: per K-step { stage(t+2); s_waitcnt vmcnt(8); s_barrier; compute(t);
// s_barrier }. vmcnt(8) leaves tiles t+1,t+2 (8 loads) in flight across the barriers --
// loads age ~2 full iterations before being required, so the drain stall of the
// __syncthreads-based loop (R0/R3) is eliminated. Hazards: RAW by vmcnt+barrier-A
// (everyone's tile-t loads done); WAR by barrier-B (iter t+1 stages into buf t%3 only
// after all waves consumed their ds_reads of it).
// LDS swizzle (verified R3): slot = chunk ^ ((row>>1)&3), pre-applied on the GLOBAL
// source chunk (LDS linear for global_load_lds); fragment reads q4 ^ ((l15>>1)&3).
// Bijective XCD swizzle on flattened id (nwg % 8 == 0); MODE 1: one batch per XCD.
// MODE 0: qkv  (N=1536) -> split bf16 q/k/v
// MODE 1: attn (per-batch 2048x2048) -> f32 * SCALE
template <int MODE>
__global__ __launch_bounds__(256) void gemm_bt(const unsigned short* __restrict__ A,
                                               const unsigned short* __restrict__ Bt,
                                               float* __restrict__ outF,
                                               unsigned short* __restrict__ outQ,
                                               unsigned short* __restrict__ outK,
                                               unsigned short* __restrict__ outV,
                                               const float* __restrict__ bias) {
    constexpr int K = 512;
    constexpr int NT = K / 32;   // 16 K-tiles
    int t = threadIdx.x;
    int lane = t & 63, wave = t >> 6;
    int wm = (wave & 1) * 64, wn = (wave >> 1) * 64;

    // ---- bijective XCD swizzle of the flattened block id ----
    int gx = gridDim.x, gy = gridDim.y;
    int nwg = gx * gy * gridDim.z;                    // divisible by 8
    int lid = blockIdx.x + gx * (blockIdx.y + gy * blockIdx.z);
    int swz = (lid & 7) * (nwg >> 3) + (lid >> 3);
    int bx = swz % gx;
    int rem = swz / gx;
    int by = rem % gy;
    int bz = rem / gy;

    int m0 = by * 128, n0 = bx * 128;
    if (MODE == 1) {
        size_t b = (size_t)bz;
        A += b * (size_t)N_ * 512;
        Bt += b * (size_t)N_ * 512;
        outF += b * (size_t)N_ * N_;
    }
    __shared__ __align__(16) unsigned short As[3][128 * 32];
    __shared__ __align__(16) unsigned short Bs[3][128 * 32];
    floatx4 acc[4][4] = {};
    int l15 = lane & 15, q4 = lane >> 4;
    int fc = (l15 >> 1) & 3;             // fragment chunk XOR

    // staging: 1KB group = 16 rows x 64B; lane covers row grp*16+(lane>>2), slot lane&3.
    int s_r = lane >> 2;                 // row within group
    int s_c = (lane & 3) ^ ((lane >> 3) & 3);   // pre-swizzled global chunk

    auto stage = [&](int buf, int tile) {
        int k0 = tile * 32;
#pragma unroll
        for (int i = 0; i < 2; ++i) {
            int grp = wave + i * 4;                  // 0..7 (8 groups of 16 rows)
            int row = grp * 16 + s_r;
            async_ld16(A + (size_t)(m0 + row) * 512 + k0 + s_c * 8, (char*)As[buf] + grp * 1024);
            async_ld16(Bt + (size_t)(n0 + row) * 512 + k0 + s_c * 8, (char*)Bs[buf] + grp * 1024);
        }
    };
    auto compute = [&](int buf) {
        int cs = (q4 ^ fc) * 8;                      // swizzled chunk offset (elements)
        short8 af[4], bfr[4];
#pragma unroll
        for (int mi = 0; mi < 4; ++mi)
            af[mi] = *(const short8*)(&As[buf][(wm + mi * 16 + l15) * 32 + cs]);
#pragma unroll
        for (int ni = 0; ni < 4; ++ni)
            bfr[ni] = *(const short8*)(&Bs[buf][(wn + ni * 16 + l15) * 32 + cs]);
#pragma unroll
        for (int mi = 0; mi < 4; ++mi)
#pragma unroll
            for (int ni = 0; ni < 4; ++ni)
                acc[mi][ni] = __builtin_amdgcn_mfma_f32_16x16x32_bf16(af[mi], bfr[ni], acc[mi][ni], 0, 0, 0);
    };

    stage(0, 0);                          // tiles 0,1 in flight (8 loads)
    stage(1, 1);
    int bc = 0, bsn = 2;
    for (int it = 0; it < NT - 2; ++it) {
        stage(bsn, it + 2);               // 12 loads outstanding (worst case)
        asm volatile("s_waitcnt vmcnt(8)" ::: "memory");   // own tile-it loads done
        __builtin_amdgcn_s_barrier();     // -> everyone's tile-it loads done
        compute(bc);
        __builtin_amdgcn_s_barrier();     // reads of buf bc done before overwrite
        bc = (bc == 2) ? 0 : bc + 1;
        bsn = (bsn == 2) ? 0 : bsn + 1;
    }
    asm volatile("s_waitcnt vmcnt(4)" ::: "memory");       // tile NT-2 done
    __builtin_amdgcn_s_barrier();
    compute(bc);
    __builtin_amdgcn_s_barrier();
    bc = (bc == 2) ? 0 : bc + 1;
    asm volatile("s_waitcnt vmcnt(0)" ::: "memory");       // tile NT-1 done
    __builtin_amdgcn_s_barrier();
    compute(bc);

    // epilogue: D[row=q4*4+r][col=l15] per 16x16 tile
#pragma unroll
    for (int mi = 0; mi < 4; ++mi) {
#pragma unroll
        for (int ni = 0; ni < 4; ++ni) {
#pragma unroll
            for (int r = 0; r < 4; ++r) {
                int row = m0 + wm + mi * 16 + q4 * 4 + r;
                int col = n0 + wn + ni * 16 + l15;
                float v = acc[mi][ni][r];
                if (MODE == 0) {
                    unsigned short u = f2bfu(v);
                    if (col < 512)       outQ[(size_t)row * 512 + col] = u;
                    else if (col < 1024) outK[(size_t)row * 512 + col - 512] = u;
                    else                 outV[(size_t)row * 512 + col - 1024] = u;
                } else {
                    outF[(size_t)row * N_ + col] = v * 0.125f;
                }
            }
        }
    }
}

// ---------------- sliced per-(batch,cluster) softmax-collapse reduction ----------------
// e_j = exp(attn[b, dbl[j], j]);  slice sl handles rows i in [n*sl/8, n*(sl+1)/8)
// Opart[b][sl][c][d] = sum_{i in slice} e_i * v[b,shuf[i],d]   (unnormalized)
// Spart[b][sl][c]    = sum_{i in slice} e_i
__global__ __launch_bounds__(256) void cluster_reduce2(const float* __restrict__ attn,
                                                       const int* __restrict__ shuf,
                                                       const int* __restrict__ dbl,
                                                       const int* __restrict__ cstart,
                                                       const unsigned short* __restrict__ vbf,
                                                       float* __restrict__ Opart,
                                                       float* __restrict__ Spart) {
    int c = blockIdx.x, b = blockIdx.y, sl = blockIdx.z, t = threadIdx.x;
    int start = cstart[b * 17 + c], end = cstart[b * 17 + c + 1];
    int n = end - start;
    int i0 = (n * sl) / SL_, i1 = (n * (sl + 1)) / SL_;
    int cnt = i1 - i0;                 // <= ceil(2048/8) = 256
    __shared__ float e_lds[256];
    __shared__ int row_lds[256];
    if (t < cnt) {
        int j = start + i0 + t;
        int dj = dbl[(size_t)b * N_ + j];
        float e = expf(attn[(size_t)b * N_ * N_ + (size_t)dj * N_ + j]);
        e_lds[t] = e;
        row_lds[t] = shuf[(size_t)b * N_ + j];
    }
    __syncthreads();
    if (t == 0) {
        float s = 0.f;
        for (int i = 0; i < cnt; ++i) s += e_lds[i];
        Spart[(b * SL_ + sl) * NC_ + c] = s;
    }
    float a0 = 0.f, a1 = 0.f;
    for (int i = 0; i < cnt; ++i) {
        float e = e_lds[i];
        unsigned u = *(const unsigned*)(vbf + ((size_t)b * N_ + row_lds[i]) * 512 + 2 * t);
        a0 += e * bfu2f((unsigned short)u);
        a1 += e * bfu2f((unsigned short)(u >> 16));
    }
    float2 o; o.x = a0; o.y = a1;
    *(float2*)(Opart + (((size_t)(b * SL_ + sl) * NC_ + c) * 512 + 2 * t)) = o;
}

// ---------------- combine slice partials -> normalized Ot[b][d][c] ----------------
__global__ __launch_bounds__(256) void combine_O(const float* __restrict__ Opart,
                                                 const float* __restrict__ Spart,
                                                 float* __restrict__ Ot) {
    int c = blockIdx.x, b = blockIdx.y, t = threadIdx.x;
    float S = 0.f;
    for (int sl = 0; sl < SL_; ++sl) S += Spart[(b * SL_ + sl) * NC_ + c];
    float inv = S > 0.f ? 1.f / S : 0.f;
    float a0 = 0.f, a1 = 0.f;
    for (int sl = 0; sl < SL_; ++sl) {
        float2 o = *(const float2*)(Opart + (((size_t)(b * SL_ + sl) * NC_ + c) * 512 + 2 * t));
        a0 += o.x; a1 += o.y;
    }
    Ot[((size_t)b * 512 + 2 * t) * NC_ + c] = a0 * inv;
    Ot[((size_t)b * 512 + 2 * t + 1) * NC_ + c] = a1 * inv;
}

// ---------------- grouped projection weights (parallel, range-based) ----------------
// svals is sorted: cluster c occupies global rows [cstart[b][c], cstart[b][c+1]).
// Within group g (rows [512g, 512(g+1))): Wg[b][g][c][m] = sum_{cd=lo}^{hi-1} Wproj[cd][m],
// lo/hi = cstart clipped into the group window. No svals scan; 512 blocks, coalesced.
__global__ __launch_bounds__(256) void build_wg(const float* __restrict__ Wproj,
                                                const int* __restrict__ cstart,
                                                unsigned int* __restrict__ Wg) {
    int c = blockIdx.x;          // cluster
    int bg = blockIdx.y;         // b*4+g
    int b = bg >> 2, g = bg & 3;
    int t = threadIdx.x;
    int lo = cstart[b * 17 + c] - g * 512;
    int hi = cstart[b * 17 + c + 1] - g * 512;
    lo = lo < 0 ? 0 : lo;
    hi = hi > 512 ? 512 : hi;
    float a0 = 0.f, a1 = 0.f;
    for (int cd = lo; cd < hi; ++cd) {
        float2 w = *(const float2*)(Wproj + (size_t)cd * 512 + 2 * t);
        a0 += w.x; a1 += w.y;
    }
    Wg[(size_t)bg * NC_ * 256 + c * 256 + t] =
        (unsigned)f2bfu(a0) | ((unsigned)f2bfu(a1) << 16);   // empty range -> 0
}

// ---------------- final projection: x_out[b,n,m] = sum_c Ot[b,rq,c]*Wg[b,g,c,m] + bias[m] ----
// r = restore[b,n]; rq = r>>2; g = r&3.  K=16 contraction, O stays f32.
__global__ __launch_bounds__(256) void xout_kernel(const float* __restrict__ Ot,
                                                   const unsigned int* __restrict__ Wg,
                                                   const int* __restrict__ restore,
                                                   const float* __restrict__ bias,
                                                   float* __restrict__ xout) {
    int nb = blockIdx.x, b = blockIdx.y, t = threadIdx.x;
    int n0 = nb * 64;
    __shared__ int r_lds[64];
    if (t < 64) r_lds[t] = restore[(size_t)b * N_ + n0 + t];
    __syncthreads();
    float b0 = bias[2 * t], b1 = bias[2 * t + 1];
    const float* Otb = Ot + (size_t)b * 512 * NC_;
    for (int g = 0; g < 4; ++g) {
        const unsigned int* wg = Wg + (size_t)(b * 4 + g) * NC_ * 256 + t;
        float wx[NC_], wy[NC_];
#pragma unroll
        for (int c = 0; c < NC_; ++c) {
            unsigned u = wg[c * 256];
            wx[c] = bfu2f((unsigned short)u);
            wy[c] = bfu2f((unsigned short)(u >> 16));
        }
        for (int i = 0; i < 64; ++i) {
            int r = r_lds[i];                    // block-uniform
            if ((r & 3) != g) continue;          // uniform branch
            int rq = r >> 2;
            const float4* op = (const float4*)(Otb + rq * NC_);
            float o[NC_];
            *(float4*)&o[0]  = op[0];
            *(float4*)&o[4]  = op[1];
            *(float4*)&o[8]  = op[2];
            *(float4*)&o[12] = op[3];
            float a0 = b0, a1 = b1;
#pragma unroll
            for (int c = 0; c < NC_; ++c) { a0 += o[c] * wx[c]; a1 += o[c] * wy[c]; }
            float2 res; res.x = a0; res.y = a1;
            *(float2*)(xout + ((size_t)b * N_ + n0 + i) * 512 + 2 * t) = res;
        }
    }
}

// ---------------- launch ----------------
extern "C" void kernel_launch(void* const* d_in, const int* in_sizes, int n_in,
                              void* d_out, int out_size, void* d_ws, size_t ws_size,
                              hipStream_t stream) {
    const float* x_token = (const float*)d_in[0];
    const int* idx_cluster = (const int*)d_in[2];
    const float* Wqk = (const float*)d_in[4];
    const float* Wv = (const float*)d_in[5];
    const float* Wproj = (const float*)d_in[7];
    const float* bproj = (const float*)d_in[8];

    float* x_out = (float*)d_out;                               // [8][2048][512]
    float* attn = x_out + (size_t)B_ * N_ * C_;                 // [8][2048][2048]

    char* ws = (char*)d_ws;
    size_t off = 0;
    auto alloc = [&](size_t bytes) {
        void* p = ws + off;
        off += (bytes + 255) & ~(size_t)255;
        return p;
    };
    unsigned short* WqkvT = (unsigned short*)alloc(1536 * 512 * 2);
    unsigned short* xbf = (unsigned short*)alloc((size_t)B_ * N_ * C_ * 2);
    unsigned short* qbf = (unsigned short*)alloc((size_t)B_ * N_ * C_ * 2);
    unsigned short* kbf = (unsigned short*)alloc((size_t)B_ * N_ * C_ * 2);
    unsigned short* vbf = (unsigned short*)alloc((size_t)B_ * N_ * C_ * 2);
    int* shuf = (int*)alloc((size_t)B_ * N_ * 4);
    int* restore = (int*)alloc((size_t)B_ * N_ * 4);
    int* svals = (int*)alloc((size_t)B_ * N_ * 4);
    int* dbl = (int*)alloc((size_t)B_ * N_ * 4);
    int* cstart = (int*)alloc(B_ * 17 * 4);
    float* Ot = (float*)alloc((size_t)B_ * 512 * NC_ * 4);
    float* Opart = (float*)alloc((size_t)B_ * SL_ * NC_ * 512 * 4);   // 2 MB
    float* Spart = (float*)alloc((size_t)B_ * SL_ * NC_ * 4);
    unsigned int* Wg = (unsigned int*)alloc((size_t)B_ * 4 * NC_ * 256 * 4);  // bf16 pairs

    // 1. converts
    cvt_x<<<dim3((B_ * N_ * C_) / (256 * 4)), dim3(256), 0, stream>>>((const float4*)x_token, xbf);
    cvt_wqkv<<<dim3((1536 * 512) / 256), dim3(256), 0, stream>>>(Wqk, Wv, WqkvT);

    // 2. stable sort / index tables
    sort_kernel<<<dim3(B_), dim3(256), 0, stream>>>(idx_cluster, shuf, restore, svals, dbl, cstart);

    // 3. grouped projection weights (range-based from cstart)
    build_wg<<<dim3(NC_, B_ * 4), dim3(256), 0, stream>>>(Wproj, cstart, Wg);

    // 4. fused qkv GEMM: [16384x512] @ [512x1536]
    gemm_bt<0><<<dim3(1536 / 128, 16384 / 128, 1), dim3(256), 0, stream>>>(
        xbf, WqkvT, nullptr, qbf, kbf, vbf, nullptr);

    // 5. attn_map = q @ k^T * SCALE  (per batch) -> output chunk 1
    gemm_bt<1><<<dim3(N_ / 128, N_ / 128, B_), dim3(256), 0, stream>>>(
        qbf, kbf, attn, nullptr, nullptr, nullptr, nullptr);

    // 6. sliced softmax-collapse per (batch, cluster, slice)
    cluster_reduce2<<<dim3(NC_, B_, SL_), dim3(256), 0, stream>>>(
        attn, shuf, dbl, cstart, vbf, Opart, Spart);

    // 7. combine slices -> normalized Ot
    combine_O<<<dim3(NC_, B_), dim3(256), 0, stream>>>(Opart, Spart, Ot);

    // 8. x_out = gather-K16-GEMM + bias -> output chunk 0
    xout_kernel<<<dim3(N_ / 64, B_), dim3(256), 0, stream>>>(Ot, Wg, restore, bproj, x_out);
}